// Round 3
// baseline (11183.420 us; speedup 1.0000x reference)
//
#include <hip/hip_runtime.h>
#include <math.h>

typedef float4 f4;

#define T_SEQ 2048
#define D_MOD 1024

__device__ __forceinline__ float gelu_f(float x){
    float u = 0.7978845608028654f*(x + 0.044715f*x*x*x);
    return 0.5f*x*(1.0f + tanhf(u));
}

// C[M,N] = act(A[M,K] @ W[K,N] + bias) (+ res)
// 64x128 block tile, 4x8 per thread (1.5 B/FMA), BK=32, reg-prefetched.
// Accumulation strictly k-sequential per output -> bitwise stable.
__global__ __launch_bounds__(256) void gemm128(
    const float* __restrict__ A, const float* __restrict__ W,
    const float* __restrict__ bias, const float* __restrict__ res,
    float* __restrict__ C, int M, int N, int K, int act, int hasres)
{
    __shared__ float As[32][68];
    __shared__ float Ws[32][136];
    const int tid = threadIdx.x;
    const int row0 = blockIdx.y*64, col0 = blockIdx.x*128;
    const int ty = tid>>4, tx = tid&15;
    const int am = tid>>2, ak = (tid&3)*8;
    const int wk = tid>>3, wn = (tid&7)*16;
    const float* Ap = A + (size_t)(row0+am)*K + ak;
    const float* Wp = W + (size_t)wk*N + col0 + wn;

    f4 a0,a1,w0,w1,w2,w3;
    a0 = *(const f4*)(Ap);
    a1 = *(const f4*)(Ap + 4);
    w0 = *(const f4*)(Wp);
    w1 = *(const f4*)(Wp + 4);
    w2 = *(const f4*)(Wp + 8);
    w3 = *(const f4*)(Wp + 12);
    As[ak+0][am]=a0.x; As[ak+1][am]=a0.y; As[ak+2][am]=a0.z; As[ak+3][am]=a0.w;
    As[ak+4][am]=a1.x; As[ak+5][am]=a1.y; As[ak+6][am]=a1.z; As[ak+7][am]=a1.w;
    *(f4*)&Ws[wk][wn]    = w0;
    *(f4*)&Ws[wk][wn+4]  = w1;
    *(f4*)&Ws[wk][wn+8]  = w2;
    *(f4*)&Ws[wk][wn+12] = w3;
    __syncthreads();

    float acc[4][8];
    #pragma unroll
    for (int i=0;i<4;i++){
        #pragma unroll
        for (int j=0;j<8;j++) acc[i][j]=0.f;
    }

    int k0 = 0;
    while (true){
        const int kn = k0 + 32;
        const bool more = kn < K;
        if (more){
            a0 = *(const f4*)(Ap + kn);
            a1 = *(const f4*)(Ap + kn + 4);
            w0 = *(const f4*)(Wp + (size_t)kn*N);
            w1 = *(const f4*)(Wp + (size_t)kn*N + 4);
            w2 = *(const f4*)(Wp + (size_t)kn*N + 8);
            w3 = *(const f4*)(Wp + (size_t)kn*N + 12);
        }
        #pragma unroll
        for (int kk=0;kk<32;kk++){
            f4 a  = *(const f4*)&As[kk][ty*4];
            f4 wA = *(const f4*)&Ws[kk][tx*8];
            f4 wB = *(const f4*)&Ws[kk][tx*8+4];
            float ar[4] = {a.x,a.y,a.z,a.w};
            #pragma unroll
            for (int i=0;i<4;i++){
                acc[i][0] += ar[i]*wA.x;
                acc[i][1] += ar[i]*wA.y;
                acc[i][2] += ar[i]*wA.z;
                acc[i][3] += ar[i]*wA.w;
                acc[i][4] += ar[i]*wB.x;
                acc[i][5] += ar[i]*wB.y;
                acc[i][6] += ar[i]*wB.z;
                acc[i][7] += ar[i]*wB.w;
            }
        }
        __syncthreads();
        if (!more) break;
        As[ak+0][am]=a0.x; As[ak+1][am]=a0.y; As[ak+2][am]=a0.z; As[ak+3][am]=a0.w;
        As[ak+4][am]=a1.x; As[ak+5][am]=a1.y; As[ak+6][am]=a1.z; As[ak+7][am]=a1.w;
        *(f4*)&Ws[wk][wn]    = w0;
        *(f4*)&Ws[wk][wn+4]  = w1;
        *(f4*)&Ws[wk][wn+8]  = w2;
        *(f4*)&Ws[wk][wn+12] = w3;
        __syncthreads();
        k0 = kn;
    }

    #pragma unroll
    for (int i=0;i<4;i++){
        const int r = row0 + ty*4 + i;
        #pragma unroll
        for (int half=0; half<2; ++half){
            const int cb = col0 + tx*8 + half*4;
            f4 bv = *(const f4*)(bias + cb);
            float t0 = acc[i][half*4+0] + bv.x;
            float t1 = acc[i][half*4+1] + bv.y;
            float t2 = acc[i][half*4+2] + bv.z;
            float t3 = acc[i][half*4+3] + bv.w;
            if (act==1){ t0=fmaxf(t0,0.f); t1=fmaxf(t1,0.f); t2=fmaxf(t2,0.f); t3=fmaxf(t3,0.f); }
            else if (act==2){ t0=gelu_f(t0); t1=gelu_f(t1); t2=gelu_f(t2); t3=gelu_f(t3); }
            if (hasres){
                f4 rv = *(const f4*)(res + (size_t)r*N + cb);
                t0+=rv.x; t1+=rv.y; t2+=rv.z; t3+=rv.w;
            }
            f4 o; o.x=t0; o.y=t1; o.z=t2; o.w=t3;
            *(f4*)(C + (size_t)r*N + cb) = o;
        }
    }
}

__global__ __launch_bounds__(256) void lnrow(
    const float* __restrict__ X, const float* __restrict__ g,
    const float* __restrict__ b, float* __restrict__ out, float eps)
{
    __shared__ float red[4];
    const int row = blockIdx.x, tid = threadIdx.x;
    const float* xp = X + (size_t)row*D_MOD;
    f4 xv = *(const f4*)(xp + tid*4);
    float s = xv.x+xv.y+xv.z+xv.w;
    #pragma unroll
    for (int m=1;m<64;m<<=1) s += __shfl_xor(s, m);
    const int wid = tid>>6, lane = tid&63;
    if (lane==0) red[wid]=s;
    __syncthreads();
    float mean = (red[0]+red[1]+red[2]+red[3]) * (1.0f/1024.0f);
    __syncthreads();
    float d0=xv.x-mean, d1=xv.y-mean, d2=xv.z-mean, d3=xv.w-mean;
    float q = d0*d0+d1*d1+d2*d2+d3*d3;
    #pragma unroll
    for (int m=1;m<64;m<<=1) q += __shfl_xor(q, m);
    if (lane==0) red[wid]=q;
    __syncthreads();
    float var = (red[0]+red[1]+red[2]+red[3]) * (1.0f/1024.0f);
    float inv = rsqrtf(var + eps);
    f4 gv = *(const f4*)(g + tid*4);
    f4 bv = *(const f4*)(b + tid*4);
    f4 o;
    o.x = d0*inv*gv.x + bv.x;
    o.y = d1*inv*gv.y + bv.y;
    o.z = d2*inv*gv.z + bv.z;
    o.w = d3*inv*gv.w + bv.w;
    *(f4*)(out + (size_t)row*D_MOD + tid*4) = o;
}

__global__ __launch_bounds__(256) void set_kv_bias(
    const float* __restrict__ bk, const float* __restrict__ bv,
    float* __restrict__ krow, float* __restrict__ vrow)
{
    const int i = threadIdx.x*4;
    *(f4*)(krow+i) = *(const f4*)(bk+i);
    *(f4*)(vrow+i) = *(const f4*)(bv+i);
}

// V-position permutation: chunk c stored at position p(c); PV reads positions
// tx (chunks 2tx -> d=8tx..+3) and 16+tx (chunks 2tx+1) -> contiguous, conflict-free.
#define PV_SJ(sj, comp) { \
    const int s_ = s4*4 + sj; \
    const f4* vrow_ = (const f4*)&vs[s_][0]; \
    const f4 v0_ = vrow_[tx]; \
    const f4 v1_ = vrow_[16+tx]; \
    const float pr_[4] = {pv0.comp, pv1.comp, pv2.comp, pv3.comp}; \
    _Pragma("unroll") \
    for (int ri_=0; ri_<4; ++ri_){ \
        const float p_ = pr_[ri_]; \
        oa[ri_][0]+=p_*v0_.x; oa[ri_][1]+=p_*v0_.y; oa[ri_][2]+=p_*v0_.z; oa[ri_][3]+=p_*v0_.w; \
        oa[ri_][4]+=p_*v1_.x; oa[ri_][5]+=p_*v1_.y; oa[ri_][6]+=p_*v1_.z; oa[ri_][7]+=p_*v1_.w; \
    } }

// flash attention: one block per (64-query tile, head); K/V length 2049.
// h = bid&7 -> each XCD's L2 caches one head's K/V panel.
// Race-free 3-barrier pipeline: QK | b1 | K-write+K-prefetch+softmax | b2 | PV | b3 | V-write+V-prefetch.
__global__ __launch_bounds__(256,1) void attn64(
    const float* __restrict__ Q, const float* __restrict__ Kb,
    const float* __restrict__ Vb, float* __restrict__ O)
{
    __shared__ float qs[64][132];
    __shared__ float ks[64][132];
    __shared__ float vs[64][132];
    __shared__ float ps[64][68];
    const int tid = threadIdx.x;
    const int h = blockIdx.x & 7;
    const int q0 = (blockIdx.x >> 3) * 64;
    const int ty = tid>>4, tx = tid&15;
    const int rbase = tid>>5, c4 = tid&31;
    const int pc4 = (c4>>1) | ((c4&1)<<4);
    const float qscale = 0.08838834764831845f; // 1/sqrt(128)

    f4 kr[8], vr[8];
    // tile 0 loads (issued first, overlap Q staging)
    #pragma unroll
    for (int j=0;j<8;j++){
        const int r = rbase + 8*j;
        kr[j] = *(const f4*)(Kb + (size_t)r*D_MOD + h*128 + c4*4);
        vr[j] = *(const f4*)(Vb + (size_t)r*D_MOD + h*128 + c4*4);
    }
    for (int i=tid; i<2048; i+=256){
        int r = i>>5, cc = i&31;
        f4 v = *(const f4*)(Q + (size_t)(q0+r)*D_MOD + h*128 + cc*4);
        v.x*=qscale; v.y*=qscale; v.z*=qscale; v.w*=qscale;
        ((f4*)&qs[r][0])[cc ^ ((r>>2)&7)] = v;
    }
    #pragma unroll
    for (int j=0;j<8;j++){
        const int r = rbase + 8*j;
        ((f4*)&ks[r][0])[c4 ^ ((r>>2)&7)] = kr[j];
        ((f4*)&vs[r][0])[pc4] = vr[j];
    }
    // prefetch tile 1 into regs
    #pragma unroll
    for (int j=0;j<8;j++){
        const int r = 64 + rbase + 8*j;
        kr[j] = *(const f4*)(Kb + (size_t)r*D_MOD + h*128 + c4*4);
        vr[j] = *(const f4*)(Vb + (size_t)r*D_MOD + h*128 + c4*4);
    }
    __syncthreads();

    float mstat[4], lstat[4], oa[4][8];
    #pragma unroll
    for (int i=0;i<4;i++){
        mstat[i] = -__builtin_inff(); lstat[i]=0.f;
        #pragma unroll
        for (int d=0; d<8; d++) oa[i][d]=0.f;
    }

    for (int t=0; t<33; ++t){
        const int sbase = t*64;
        // ---- QK^T from ks ----
        float acc[4][4];
        #pragma unroll
        for (int i=0;i<4;i++){
            #pragma unroll
            for (int j=0;j<4;j++) acc[i][j]=0.f;
        }
        #pragma unroll 4
        for (int d4=0; d4<32; ++d4){
            f4 qv[4], kv[4];
            #pragma unroll
            for (int i=0;i<4;i++) qv[i] = ((const f4*)&qs[ty*4+i][0])[d4 ^ (ty&7)];
            #pragma unroll
            for (int j=0;j<4;j++) kv[j] = ((const f4*)&ks[tx*4+j][0])[d4 ^ (tx&7)];
            #pragma unroll
            for (int i=0;i<4;i++){
                const float ax=qv[i].x, ay=qv[i].y, az=qv[i].z, aw=qv[i].w;
                #pragma unroll
                for (int j=0;j<4;j++){
                    acc[i][j] += ax*kv[j].x + ay*kv[j].y + az*kv[j].z + aw*kv[j].w;
                }
            }
        }
        __syncthreads();   // b1: QK done, ks free

        if (t < 32){
            // write K_{t+1} (held in kr) into ks; then issue K_{t+2} loads
            #pragma unroll
            for (int j=0;j<8;j++){
                const int r = rbase + 8*j;
                ((f4*)&ks[r][0])[c4 ^ ((r>>2)&7)] = kr[j];
            }
            if (t+2 <= 32){
                const int sn = (t+2)*64;
                #pragma unroll
                for (int j=0;j<8;j++){
                    const int gr = sn + rbase + 8*j;
                    if (gr < 2049)
                        kr[j] = *(const f4*)(Kb + (size_t)gr*D_MOD + h*128 + c4*4);
                }
            }
        }

        // ---- softmax ----
        #pragma unroll
        for (int i=0;i<4;i++){
            float tm = -__builtin_inff();
            #pragma unroll
            for (int j=0;j<4;j++){
                int s = sbase + tx*4 + j;
                if (s >= 2049) acc[i][j] = -__builtin_inff();
                tm = fmaxf(tm, acc[i][j]);
            }
            tm = fmaxf(tm, __shfl_xor(tm,1));
            tm = fmaxf(tm, __shfl_xor(tm,2));
            tm = fmaxf(tm, __shfl_xor(tm,4));
            tm = fmaxf(tm, __shfl_xor(tm,8));
            float mn = fmaxf(mstat[i], tm);
            float sc = __expf(mstat[i] - mn);
            float rs = 0.f;
            #pragma unroll
            for (int j=0;j<4;j++){
                float p = __expf(acc[i][j] - mn);
                acc[i][j] = p;
                rs += p;
            }
            rs += __shfl_xor(rs,1); rs += __shfl_xor(rs,2);
            rs += __shfl_xor(rs,4); rs += __shfl_xor(rs,8);
            lstat[i] = lstat[i]*sc + rs;
            mstat[i] = mn;
            #pragma unroll
            for (int d=0; d<8; d++) oa[i][d] *= sc;
            f4 pw; pw.x=acc[i][0]; pw.y=acc[i][1]; pw.z=acc[i][2]; pw.w=acc[i][3];
            *(f4*)&ps[ty*4+i][tx*4] = pw;
        }
        __syncthreads();   // b2: ps ready (K-write also covered)

        // ---- PV from vs (position-permuted layout) ----
        #pragma unroll 4
        for (int s4=0; s4<16; ++s4){
            f4 pv0 = *(const f4*)&ps[ty*4+0][s4*4];
            f4 pv1 = *(const f4*)&ps[ty*4+1][s4*4];
            f4 pv2 = *(const f4*)&ps[ty*4+2][s4*4];
            f4 pv3 = *(const f4*)&ps[ty*4+3][s4*4];
            PV_SJ(0, x)
            PV_SJ(1, y)
            PV_SJ(2, z)
            PV_SJ(3, w)
        }
        __syncthreads();   // b3: PV done, vs free

        if (t < 32){
            // write V_{t+1} (held in vr) into vs; then issue V_{t+2} loads
            #pragma unroll
            for (int j=0;j<8;j++){
                const int r = rbase + 8*j;
                ((f4*)&vs[r][0])[pc4] = vr[j];
            }
            if (t+2 <= 32){
                const int sn = (t+2)*64;
                #pragma unroll
                for (int j=0;j<8;j++){
                    const int gr = sn + rbase + 8*j;
                    if (gr < 2049)
                        vr[j] = *(const f4*)(Vb + (size_t)gr*D_MOD + h*128 + c4*4);
                }
            }
        }
    }

    #pragma unroll
    for (int i=0;i<4;i++){
        const float inv = 1.0f / lstat[i];
        f4 o0, o1;
        o0.x=oa[i][0]*inv; o0.y=oa[i][1]*inv; o0.z=oa[i][2]*inv; o0.w=oa[i][3]*inv;
        o1.x=oa[i][4]*inv; o1.y=oa[i][5]*inv; o1.z=oa[i][6]*inv; o1.w=oa[i][7]*inv;
        float* dst = O + (size_t)(q0+ty*4+i)*D_MOD + h*128 + tx*8;
        *(f4*)dst = o0;
        *(f4*)(dst+4) = o1;
    }
}

__global__ __launch_bounds__(64) void locate_head(
    const float* __restrict__ mid, const float* __restrict__ W2,
    const float* __restrict__ b2, float* __restrict__ loc_ws,
    float* __restrict__ loc_out)
{
    const int row = blockIdx.x, lane = threadIdx.x;
    const float* m = mid + (size_t)row*512;
    f4 v0 = *(const f4*)(m + lane*8);
    f4 v1 = *(const f4*)(m + lane*8 + 4);
    f4 w0 = *(const f4*)(W2 + lane*8);
    f4 w1 = *(const f4*)(W2 + lane*8 + 4);
    float s = v0.x*w0.x + v0.y*w0.y + v0.z*w0.z + v0.w*w0.w
            + v1.x*w1.x + v1.y*w1.y + v1.z*w1.z + v1.w*w1.w;
    #pragma unroll
    for (int mm=1; mm<64; mm<<=1) s += __shfl_xor(s, mm);
    if (lane==0){
        float z = s + b2[0];
        float l = 1.0f/(1.0f + expf(-z));
        loc_ws[row] = l;
        loc_out[row] = l;
    }
}

__global__ __launch_bounds__(1024) void segscan(
    const float* __restrict__ located, const float* __restrict__ thrp,
    float* __restrict__ out_segid, float* __restrict__ out_segtype,
    float* __restrict__ out_numseg, int* __restrict__ wsi)
{
    __shared__ int clips[2048];
    __shared__ int segid[2048];
    __shared__ int sstart[2049];
    __shared__ int wsum[16];
    const int tid = threadIdx.x;
    const float thr = *thrp;
    for (int t=tid; t<2048; t+=1024) clips[t] = (located[t] > thr) ? 1 : 0;
    __syncthreads();
    const int t0 = tid*2, t1 = t0+1;
    int f0 = (t0==0) ? 0 : (clips[t0]!=clips[t0-1] ? 1 : 0);
    int f1 = (clips[t1]!=clips[t1-1] ? 1 : 0);
    int e0 = f0, e1 = f0+f1;
    const int lane = tid&63, wid = tid>>6;
    int v = e1;
    #pragma unroll
    for (int off=1; off<64; off<<=1){
        int u = __shfl_up(v, off, 64);
        if (lane>=off) v += u;
    }
    if (lane==63) wsum[wid] = v;
    __syncthreads();
    if (tid < 16){
        int w = wsum[tid];
        #pragma unroll
        for (int off=1; off<16; off<<=1){
            int u = __shfl_up(w, off, 16);
            if (tid>=off) w += u;
        }
        wsum[tid] = w;
    }
    __syncthreads();
    int base = (wid>0 ? wsum[wid-1] : 0) + (v - e1);
    segid[t0] = base + e0;
    segid[t1] = base + e1;
    __syncthreads();
    const int ns = segid[2047] + 1;
    for (int t=tid; t<2048; t+=1024){
        if (t==0 || segid[t]!=segid[t-1]) sstart[segid[t]] = t;
    }
    if (tid==0) sstart[ns] = 2048;
    __syncthreads();
    for (int t=tid; t<2048; t+=1024) out_segid[t] = (float)segid[t];
    for (int s=tid; s<2048; s+=1024)
        out_segtype[s] = (s<ns) ? (float)clips[sstart[s]] : -2147483648.0f;
    if (tid==0){ out_numseg[0] = (float)ns; wsi[0] = ns; }
    for (int s=tid; s<=2048; s+=1024) wsi[2+s] = (s<=ns) ? sstart[s] : 0;
}

__global__ __launch_bounds__(256) void segpool(
    const float* __restrict__ V, const float* __restrict__ A,
    const int* __restrict__ wsi, float* __restrict__ out_vid,
    float* __restrict__ out_aud)
{
    const int s = blockIdx.x;
    const int c = threadIdx.x*4;
    const int ns = wsi[0];
    f4 vv; vv.x=0.f; vv.y=0.f; vv.z=0.f; vv.w=0.f;
    f4 av = vv;
    if (s < ns){
        const int st = wsi[2+s], en = wsi[2+s+1];
        for (int r=st; r<en; ++r){
            f4 x = *(const f4*)(V + (size_t)r*D_MOD + c);
            vv.x+=x.x; vv.y+=x.y; vv.z+=x.z; vv.w+=x.w;
            f4 y = *(const f4*)(A + (size_t)r*D_MOD + c);
            av.x+=y.x; av.y+=y.y; av.z+=y.z; av.w+=y.w;
        }
        const float inv = 1.0f/(float)(en-st);
        vv.x*=inv; vv.y*=inv; vv.z*=inv; vv.w*=inv;
        av.x*=inv; av.y*=inv; av.z*=inv; av.w*=inv;
    }
    *(f4*)(out_vid + (size_t)s*D_MOD + c) = vv;
    *(f4*)(out_aud + (size_t)s*D_MOD + c) = av;
}

extern "C" void kernel_launch(void* const* d_in, const int* in_sizes, int n_in,
                              void* d_out, int out_size, void* d_ws, size_t ws_size,
                              hipStream_t stream) {
    (void)in_sizes; (void)n_in; (void)out_size; (void)ws_size;
    const float* video = (const float*)d_in[0];
    const float* audio = (const float*)d_in[1];
    const float* apW1  = (const float*)d_in[2];
    const float* apb1  = (const float*)d_in[3];
    const float* apW2  = (const float*)d_in[4];
    const float* apb2  = (const float*)d_in[5];
    const float* vpW1  = (const float*)d_in[6];
    const float* vpb1  = (const float*)d_in[7];
    const float* vpW2  = (const float*)d_in[8];
    const float* vpb2  = (const float*)d_in[9];
    const float* preg  = (const float*)d_in[10];
    const float* preb  = (const float*)d_in[11];
    const float* bWq   = (const float*)d_in[12];
    const float* bbq   = (const float*)d_in[13];
    const float* bWk   = (const float*)d_in[14];
    const float* bbk   = (const float*)d_in[15];
    const float* bWv   = (const float*)d_in[16];
    const float* bbv   = (const float*)d_in[17];
    const float* bWo   = (const float*)d_in[18];
    const float* bbo   = (const float*)d_in[19];
    const float* bbiask= (const float*)d_in[20];
    const float* bbiasv= (const float*)d_in[21];
    const float* bg1   = (const float*)d_in[22];
    const float* bb1   = (const float*)d_in[23];
    const float* bg2   = (const float*)d_in[24];
    const float* bb2   = (const float*)d_in[25];
    const float* bmW1  = (const float*)d_in[26];
    const float* bmb1  = (const float*)d_in[27];
    const float* bmW2  = (const float*)d_in[28];
    const float* bmb2  = (const float*)d_in[29];
    const float* lhW1  = (const float*)d_in[30];
    const float* lhb1  = (const float*)d_in[31];
    const float* lhW2  = (const float*)d_in[32];
    const float* lhb2  = (const float*)d_in[33];
    const float* thrp  = (const float*)d_in[34];

    float* ws = (float*)d_ws;
    float* V   = ws + 0;
    float* Abuf= ws + 2097152;
    float* X   = ws + 4194304;
    float* H   = ws + 6291456;
    float* Q    = ws + 8388608;
    float* Kb   = ws + 10485760;            // 2049*1024
    float* Vb   = ws + 12583936;            // 2049*1024
    float* Obuf = ws + 14682112;            // 2048*1024
    float* M4   = ws + 8388608;             // 2048*4096, aliases Q..O
    float* M512 = ws + 16779264;            // 2048*512
    float* LOC  = ws + 17827840;            // 2048
    int*   WSI  = (int*)(ws + 17829888);    // [0]=ns, [2..2050]=sstart

    float* out = (float*)d_out;
    float* out_vid     = out + 0;
    float* out_aud     = out + 2097152;
    float* out_loc     = out + 4194304;
    float* out_segid   = out + 4196352;
    float* out_segtype = out + 4198400;
    float* out_numseg  = out + 4200448;

    const dim3 B256(256);
    #define GRID128(M,N) dim3((N)/128,(M)/64)

    // projectors
    gemm128<<<GRID128(2048,512), B256, 0, stream>>>(audio, apW1, apb1, nullptr, M512, 2048,512,128, 1,0);
    gemm128<<<GRID128(2048,1024),B256, 0, stream>>>(M512, apW2, apb2, nullptr, Abuf, 2048,1024,512, 0,0);
    gemm128<<<GRID128(2048,512), B256, 0, stream>>>(video, vpW1, vpb1, nullptr, M512, 2048,512,1024, 1,0);
    gemm128<<<GRID128(2048,1024),B256, 0, stream>>>(M512, vpW2, vpb2, nullptr, V,    2048,1024,512, 0,0);
    lnrow<<<2048, B256, 0, stream>>>(Abuf, preg, preb, X, 1e-6f);

    for (int l=0; l<8; ++l){
        const size_t wo = (size_t)l*1024*1024;
        const size_t bo = (size_t)l*1024;
        const size_t mo1 = (size_t)l*1024*4096;
        lnrow<<<2048, B256, 0, stream>>>(X, bg1+bo, bb1+bo, H, 1e-5f);
        gemm128<<<GRID128(2048,1024),B256,0,stream>>>(H, bWq+wo, bbq+bo, nullptr, Q,  2048,1024,1024, 0,0);
        gemm128<<<GRID128(2048,1024),B256,0,stream>>>(V, bWk+wo, bbk+bo, nullptr, Kb, 2048,1024,1024, 0,0);
        gemm128<<<GRID128(2048,1024),B256,0,stream>>>(V, bWv+wo, bbv+bo, nullptr, Vb, 2048,1024,1024, 0,0);
        set_kv_bias<<<1, B256, 0, stream>>>(bbiask+bo, bbiasv+bo, Kb + (size_t)2048*1024, Vb + (size_t)2048*1024);
        attn64<<<256, B256, 0, stream>>>(Q, Kb, Vb, Obuf);
        gemm128<<<GRID128(2048,1024),B256,0,stream>>>(Obuf, bWo+wo, bbo+bo, X, X, 2048,1024,1024, 0,1);
        lnrow<<<2048, B256, 0, stream>>>(X, bg2+bo, bb2+bo, H, 1e-5f);
        gemm128<<<GRID128(2048,4096),B256,0,stream>>>(H, bmW1+mo1, bmb1+(size_t)l*4096, nullptr, M4, 2048,4096,1024, 2,0);
        gemm128<<<GRID128(2048,1024),B256,0,stream>>>(M4, bmW2+mo1, bmb2+bo, X, X, 2048,1024,4096, 0,1);
    }

    gemm128<<<GRID128(2048,512), B256, 0, stream>>>(X, lhW1, lhb1, nullptr, M512, 2048,512,1024, 1,0);
    locate_head<<<2048, dim3(64), 0, stream>>>(M512, lhW2, lhb2, LOC, out_loc);
    segscan<<<1, dim3(1024), 0, stream>>>(LOC, thrp, out_segid, out_segtype, out_numseg, WSI);
    segpool<<<2048, B256, 0, stream>>>(V, Abuf, WSI, out_vid, out_aud);
}

// Round 4
// 9840.202 us; speedup vs baseline: 1.1365x; 1.1365x over previous
//
#include <hip/hip_runtime.h>
#include <math.h>

typedef float4 f4;

#define T_SEQ 2048
#define D_MOD 1024

__device__ __forceinline__ float gelu_f(float x){
    float u = 0.7978845608028654f*(x + 0.044715f*x*x*x);
    return 0.5f*x*(1.0f + tanhf(u));
}

// C[M,N] = act(A[M,K] @ W[K,N] + bias) (+ res)
// 64x128 block tile, 4x8 per thread, BK=32, reg-prefetched.
// Accumulation strictly k-sequential per output -> bitwise stable.
__global__ __launch_bounds__(256) void gemm128(
    const float* __restrict__ A, const float* __restrict__ W,
    const float* __restrict__ bias, const float* __restrict__ res,
    float* __restrict__ C, int M, int N, int K, int act, int hasres)
{
    __shared__ float As[32][68];
    __shared__ float Ws[32][136];
    const int tid = threadIdx.x;
    const int row0 = blockIdx.y*64, col0 = blockIdx.x*128;
    const int ty = tid>>4, tx = tid&15;
    const int am = tid>>2, ak = (tid&3)*8;
    const int wk = tid>>3, wn = (tid&7)*16;
    const float* Ap = A + (size_t)(row0+am)*K + ak;
    const float* Wp = W + (size_t)wk*N + col0 + wn;

    f4 a0,a1,w0,w1,w2,w3;
    a0 = *(const f4*)(Ap);
    a1 = *(const f4*)(Ap + 4);
    w0 = *(const f4*)(Wp);
    w1 = *(const f4*)(Wp + 4);
    w2 = *(const f4*)(Wp + 8);
    w3 = *(const f4*)(Wp + 12);
    As[ak+0][am]=a0.x; As[ak+1][am]=a0.y; As[ak+2][am]=a0.z; As[ak+3][am]=a0.w;
    As[ak+4][am]=a1.x; As[ak+5][am]=a1.y; As[ak+6][am]=a1.z; As[ak+7][am]=a1.w;
    *(f4*)&Ws[wk][wn]    = w0;
    *(f4*)&Ws[wk][wn+4]  = w1;
    *(f4*)&Ws[wk][wn+8]  = w2;
    *(f4*)&Ws[wk][wn+12] = w3;
    __syncthreads();

    float acc[4][8];
    #pragma unroll
    for (int i=0;i<4;i++){
        #pragma unroll
        for (int j=0;j<8;j++) acc[i][j]=0.f;
    }

    int k0 = 0;
    while (true){
        const int kn = k0 + 32;
        const bool more = kn < K;
        if (more){
            a0 = *(const f4*)(Ap + kn);
            a1 = *(const f4*)(Ap + kn + 4);
            w0 = *(const f4*)(Wp + (size_t)kn*N);
            w1 = *(const f4*)(Wp + (size_t)kn*N + 4);
            w2 = *(const f4*)(Wp + (size_t)kn*N + 8);
            w3 = *(const f4*)(Wp + (size_t)kn*N + 12);
        }
        #pragma unroll
        for (int kk=0;kk<32;kk++){
            f4 a  = *(const f4*)&As[kk][ty*4];
            f4 wA = *(const f4*)&Ws[kk][tx*8];
            f4 wB = *(const f4*)&Ws[kk][tx*8+4];
            float ar[4] = {a.x,a.y,a.z,a.w};
            #pragma unroll
            for (int i=0;i<4;i++){
                acc[i][0] += ar[i]*wA.x;
                acc[i][1] += ar[i]*wA.y;
                acc[i][2] += ar[i]*wA.z;
                acc[i][3] += ar[i]*wA.w;
                acc[i][4] += ar[i]*wB.x;
                acc[i][5] += ar[i]*wB.y;
                acc[i][6] += ar[i]*wB.z;
                acc[i][7] += ar[i]*wB.w;
            }
        }
        __syncthreads();
        if (!more) break;
        As[ak+0][am]=a0.x; As[ak+1][am]=a0.y; As[ak+2][am]=a0.z; As[ak+3][am]=a0.w;
        As[ak+4][am]=a1.x; As[ak+5][am]=a1.y; As[ak+6][am]=a1.z; As[ak+7][am]=a1.w;
        *(f4*)&Ws[wk][wn]    = w0;
        *(f4*)&Ws[wk][wn+4]  = w1;
        *(f4*)&Ws[wk][wn+8]  = w2;
        *(f4*)&Ws[wk][wn+12] = w3;
        __syncthreads();
        k0 = kn;
    }

    #pragma unroll
    for (int i=0;i<4;i++){
        const int r = row0 + ty*4 + i;
        #pragma unroll
        for (int half=0; half<2; ++half){
            const int cb = col0 + tx*8 + half*4;
            f4 bv = *(const f4*)(bias + cb);
            float t0 = acc[i][half*4+0] + bv.x;
            float t1 = acc[i][half*4+1] + bv.y;
            float t2 = acc[i][half*4+2] + bv.z;
            float t3 = acc[i][half*4+3] + bv.w;
            if (act==1){ t0=fmaxf(t0,0.f); t1=fmaxf(t1,0.f); t2=fmaxf(t2,0.f); t3=fmaxf(t3,0.f); }
            else if (act==2){ t0=gelu_f(t0); t1=gelu_f(t1); t2=gelu_f(t2); t3=gelu_f(t3); }
            if (hasres){
                f4 rv = *(const f4*)(res + (size_t)r*N + cb);
                t0+=rv.x; t1+=rv.y; t2+=rv.z; t3+=rv.w;
            }
            f4 o; o.x=t0; o.y=t1; o.z=t2; o.w=t3;
            *(f4*)(C + (size_t)r*N + cb) = o;
        }
    }
}

__global__ __launch_bounds__(256) void lnrow(
    const float* __restrict__ X, const float* __restrict__ g,
    const float* __restrict__ b, float* __restrict__ out, float eps)
{
    __shared__ float red[4];
    const int row = blockIdx.x, tid = threadIdx.x;
    const float* xp = X + (size_t)row*D_MOD;
    f4 xv = *(const f4*)(xp + tid*4);
    float s = xv.x+xv.y+xv.z+xv.w;
    #pragma unroll
    for (int m=1;m<64;m<<=1) s += __shfl_xor(s, m);
    const int wid = tid>>6, lane = tid&63;
    if (lane==0) red[wid]=s;
    __syncthreads();
    float mean = (red[0]+red[1]+red[2]+red[3]) * (1.0f/1024.0f);
    __syncthreads();
    float d0=xv.x-mean, d1=xv.y-mean, d2=xv.z-mean, d3=xv.w-mean;
    float q = d0*d0+d1*d1+d2*d2+d3*d3;
    #pragma unroll
    for (int m=1;m<64;m<<=1) q += __shfl_xor(q, m);
    if (lane==0) red[wid]=q;
    __syncthreads();
    float var = (red[0]+red[1]+red[2]+red[3]) * (1.0f/1024.0f);
    float inv = rsqrtf(var + eps);
    f4 gv = *(const f4*)(g + tid*4);
    f4 bv = *(const f4*)(b + tid*4);
    f4 o;
    o.x = d0*inv*gv.x + bv.x;
    o.y = d1*inv*gv.y + bv.y;
    o.z = d2*inv*gv.z + bv.z;
    o.w = d3*inv*gv.w + bv.w;
    *(f4*)(out + (size_t)row*D_MOD + tid*4) = o;
}

// V-position permutation: chunk c stored at position p(c); PV reads positions
// tx and 16+tx -> contiguous 256B runs, conflict-free.
#define PV_SJ(sj, comp) { \
    const int s_ = s4*4 + sj; \
    const f4* vrow_ = (const f4*)&vs[s_][0]; \
    const f4 v0_ = vrow_[tx]; \
    const f4 v1_ = vrow_[16+tx]; \
    const float pr_[2] = {pv0.comp, pv1.comp}; \
    _Pragma("unroll") \
    for (int ri_=0; ri_<2; ++ri_){ \
        const float p_ = pr_[ri_]; \
        oa[ri_][0]+=p_*v0_.x; oa[ri_][1]+=p_*v0_.y; oa[ri_][2]+=p_*v0_.z; oa[ri_][3]+=p_*v0_.w; \
        oa[ri_][4]+=p_*v1_.x; oa[ri_][5]+=p_*v1_.y; oa[ri_][6]+=p_*v1_.z; oa[ri_][7]+=p_*v1_.w; \
    } }

// flash attention: 512 threads (8 waves -> 2 waves/SIMD), one block per
// (64-query tile, head). h = bid&7 -> per-XCD L2 caches one head's K/V panel.
// 32 full K/V tiles + register epilogue for the bias-KV token (s=2048).
// Pipeline: QK | b1 | K-write+K-prefetch+softmax | b2 | PV | b3 | V-write+V-prefetch.
__global__ __launch_bounds__(512) void attn64(
    const float* __restrict__ Q, const float* __restrict__ Kb,
    const float* __restrict__ Vb, const float* __restrict__ kbias,
    const float* __restrict__ vbias, float* __restrict__ O)
{
    __shared__ float qs[64][132];
    __shared__ float ks[64][132];
    __shared__ float vs[64][132];
    __shared__ float ps[64][68];
    const int tid = threadIdx.x;
    const int h = blockIdx.x & 7;
    const int q0 = (blockIdx.x >> 3) * 64;
    const int ty = tid>>4, tx = tid&15;         // rows ty*2..+1, s-cols tx*4..+3
    const int rbase = tid>>5, c4 = tid&31;      // loader: rows rbase+16j, chunk c4
    const int pc4 = (c4>>1) | ((c4&1)<<4);
    const int qkey = (ty>>1)&7;                 // swizzle key for rows 2ty,2ty+1
    const int kkey = tx&7;
    const float qscale = 0.08838834764831845f;  // 1/sqrt(128)

    f4 kr[4], vr[4];
    // tile 0 loads (issued first, overlap Q staging)
    #pragma unroll
    for (int j=0;j<4;j++){
        const int r = rbase + 16*j;
        kr[j] = *(const f4*)(Kb + (size_t)r*D_MOD + h*128 + c4*4);
        vr[j] = *(const f4*)(Vb + (size_t)r*D_MOD + h*128 + c4*4);
    }
    for (int i=tid; i<2048; i+=512){
        int r = i>>5, cc = i&31;
        f4 v = *(const f4*)(Q + (size_t)(q0+r)*D_MOD + h*128 + cc*4);
        v.x*=qscale; v.y*=qscale; v.z*=qscale; v.w*=qscale;
        ((f4*)&qs[r][0])[cc ^ ((r>>2)&7)] = v;
    }
    #pragma unroll
    for (int j=0;j<4;j++){
        const int r = rbase + 16*j;
        ((f4*)&ks[r][0])[c4 ^ ((r>>2)&7)] = kr[j];
        ((f4*)&vs[r][0])[pc4] = vr[j];
    }
    // prefetch tile 1 into regs
    #pragma unroll
    for (int j=0;j<4;j++){
        const int r = 64 + rbase + 16*j;
        kr[j] = *(const f4*)(Kb + (size_t)r*D_MOD + h*128 + c4*4);
        vr[j] = *(const f4*)(Vb + (size_t)r*D_MOD + h*128 + c4*4);
    }
    __syncthreads();

    float mstat[2], lstat[2], oa[2][8];
    #pragma unroll
    for (int i=0;i<2;i++){
        mstat[i] = -__builtin_inff(); lstat[i]=0.f;
        #pragma unroll
        for (int d=0; d<8; d++) oa[i][d]=0.f;
    }

    for (int t=0; t<32; ++t){
        // ---- QK^T from ks ----
        float acc[2][4];
        #pragma unroll
        for (int i=0;i<2;i++){
            #pragma unroll
            for (int j=0;j<4;j++) acc[i][j]=0.f;
        }
        #pragma unroll 4
        for (int d4=0; d4<32; ++d4){
            f4 qv[2], kv[4];
            #pragma unroll
            for (int i=0;i<2;i++) qv[i] = ((const f4*)&qs[ty*2+i][0])[d4 ^ qkey];
            #pragma unroll
            for (int j=0;j<4;j++) kv[j] = ((const f4*)&ks[tx*4+j][0])[d4 ^ kkey];
            #pragma unroll
            for (int i=0;i<2;i++){
                const float ax=qv[i].x, ay=qv[i].y, az=qv[i].z, aw=qv[i].w;
                #pragma unroll
                for (int j=0;j<4;j++){
                    acc[i][j] += ax*kv[j].x + ay*kv[j].y + az*kv[j].z + aw*kv[j].w;
                }
            }
        }
        __syncthreads();   // b1: QK done, ks free

        if (t < 31){
            // write K_{t+1} (in kr) into ks; issue K_{t+2} loads
            #pragma unroll
            for (int j=0;j<4;j++){
                const int r = rbase + 16*j;
                ((f4*)&ks[r][0])[c4 ^ ((r>>2)&7)] = kr[j];
            }
            if (t+2 <= 31){
                const int sn = (t+2)*64;
                #pragma unroll
                for (int j=0;j<4;j++){
                    const int gr = sn + rbase + 16*j;
                    kr[j] = *(const f4*)(Kb + (size_t)gr*D_MOD + h*128 + c4*4);
                }
            }
        }

        // ---- softmax (online) ----
        #pragma unroll
        for (int i=0;i<2;i++){
            float tm = fmaxf(fmaxf(acc[i][0],acc[i][1]), fmaxf(acc[i][2],acc[i][3]));
            tm = fmaxf(tm, __shfl_xor(tm,1));
            tm = fmaxf(tm, __shfl_xor(tm,2));
            tm = fmaxf(tm, __shfl_xor(tm,4));
            tm = fmaxf(tm, __shfl_xor(tm,8));
            float mn = fmaxf(mstat[i], tm);
            float sc = __expf(mstat[i] - mn);
            float rs = 0.f;
            #pragma unroll
            for (int j=0;j<4;j++){
                float p = __expf(acc[i][j] - mn);
                acc[i][j] = p;
                rs += p;
            }
            rs += __shfl_xor(rs,1); rs += __shfl_xor(rs,2);
            rs += __shfl_xor(rs,4); rs += __shfl_xor(rs,8);
            lstat[i] = lstat[i]*sc + rs;
            mstat[i] = mn;
            #pragma unroll
            for (int d=0; d<8; d++) oa[i][d] *= sc;
            f4 pw; pw.x=acc[i][0]; pw.y=acc[i][1]; pw.z=acc[i][2]; pw.w=acc[i][3];
            *(f4*)&ps[ty*2+i][tx*4] = pw;
        }
        __syncthreads();   // b2: ps ready (K-write also covered)

        // ---- PV from vs (position-permuted layout) ----
        #pragma unroll 4
        for (int s4=0; s4<16; ++s4){
            f4 pv0 = *(const f4*)&ps[ty*2+0][s4*4];
            f4 pv1 = *(const f4*)&ps[ty*2+1][s4*4];
            PV_SJ(0, x)
            PV_SJ(1, y)
            PV_SJ(2, z)
            PV_SJ(3, w)
        }
        __syncthreads();   // b3: PV done, vs free

        if (t < 31){
            #pragma unroll
            for (int j=0;j<4;j++){
                const int r = rbase + 16*j;
                ((f4*)&vs[r][0])[pc4] = vr[j];
            }
            if (t+2 <= 31){
                const int sn = (t+2)*64;
                #pragma unroll
                for (int j=0;j<4;j++){
                    const int gr = sn + rbase + 16*j;
                    vr[j] = *(const f4*)(Vb + (size_t)gr*D_MOD + h*128 + c4*4);
                }
            }
        }
    }

    // ---- epilogue: bias-KV token (s = 2048) ----
    {
        f4 kb0 = *(const f4*)(kbias + h*128 + tx*8);
        f4 kb1 = *(const f4*)(kbias + h*128 + tx*8 + 4);
        f4 vb0 = *(const f4*)(vbias + h*128 + tx*8);
        f4 vb1 = *(const f4*)(vbias + h*128 + tx*8 + 4);
        #pragma unroll
        for (int i=0;i<2;i++){
            // per-lane partial over dims tx*8..+7 (q already scaled)
            f4 q0v = ((const f4*)&qs[ty*2+i][0])[(2*tx) ^ qkey];
            f4 q1v = ((const f4*)&qs[ty*2+i][0])[(2*tx+1) ^ qkey];
            float sp = q0v.x*kb0.x + q0v.y*kb0.y + q0v.z*kb0.z + q0v.w*kb0.w
                     + q1v.x*kb1.x + q1v.y*kb1.y + q1v.z*kb1.z + q1v.w*kb1.w;
            sp += __shfl_xor(sp,1); sp += __shfl_xor(sp,2);
            sp += __shfl_xor(sp,4); sp += __shfl_xor(sp,8);
            float mn = fmaxf(mstat[i], sp);
            float sc = __expf(mstat[i] - mn);
            float p  = __expf(sp - mn);
            lstat[i] = lstat[i]*sc + p;
            mstat[i] = mn;
            #pragma unroll
            for (int d=0; d<8; d++) oa[i][d] *= sc;
            oa[i][0]+=p*vb0.x; oa[i][1]+=p*vb0.y; oa[i][2]+=p*vb0.z; oa[i][3]+=p*vb0.w;
            oa[i][4]+=p*vb1.x; oa[i][5]+=p*vb1.y; oa[i][6]+=p*vb1.z; oa[i][7]+=p*vb1.w;
        }
    }

    #pragma unroll
    for (int i=0;i<2;i++){
        const float inv = 1.0f / lstat[i];
        f4 o0, o1;
        o0.x=oa[i][0]*inv; o0.y=oa[i][1]*inv; o0.z=oa[i][2]*inv; o0.w=oa[i][3]*inv;
        o1.x=oa[i][4]*inv; o1.y=oa[i][5]*inv; o1.z=oa[i][6]*inv; o1.w=oa[i][7]*inv;
        float* dst = O + (size_t)(q0+ty*2+i)*D_MOD + h*128 + tx*8;
        *(f4*)dst = o0;
        *(f4*)(dst+4) = o1;
    }
}

__global__ __launch_bounds__(64) void locate_head(
    const float* __restrict__ mid, const float* __restrict__ W2,
    const float* __restrict__ b2, float* __restrict__ loc_ws,
    float* __restrict__ loc_out)
{
    const int row = blockIdx.x, lane = threadIdx.x;
    const float* m = mid + (size_t)row*512;
    f4 v0 = *(const f4*)(m + lane*8);
    f4 v1 = *(const f4*)(m + lane*8 + 4);
    f4 w0 = *(const f4*)(W2 + lane*8);
    f4 w1 = *(const f4*)(W2 + lane*8 + 4);
    float s = v0.x*w0.x + v0.y*w0.y + v0.z*w0.z + v0.w*w0.w
            + v1.x*w1.x + v1.y*w1.y + v1.z*w1.z + v1.w*w1.w;
    #pragma unroll
    for (int mm=1; mm<64; mm<<=1) s += __shfl_xor(s, mm);
    if (lane==0){
        float z = s + b2[0];
        float l = 1.0f/(1.0f + expf(-z));
        loc_ws[row] = l;
        loc_out[row] = l;
    }
}

__global__ __launch_bounds__(1024) void segscan(
    const float* __restrict__ located, const float* __restrict__ thrp,
    float* __restrict__ out_segid, float* __restrict__ out_segtype,
    float* __restrict__ out_numseg, int* __restrict__ wsi)
{
    __shared__ int clips[2048];
    __shared__ int segid[2048];
    __shared__ int sstart[2049];
    __shared__ int wsum[16];
    const int tid = threadIdx.x;
    const float thr = *thrp;
    for (int t=tid; t<2048; t+=1024) clips[t] = (located[t] > thr) ? 1 : 0;
    __syncthreads();
    const int t0 = tid*2, t1 = t0+1;
    int f0 = (t0==0) ? 0 : (clips[t0]!=clips[t0-1] ? 1 : 0);
    int f1 = (clips[t1]!=clips[t1-1] ? 1 : 0);
    int e0 = f0, e1 = f0+f1;
    const int lane = tid&63, wid = tid>>6;
    int v = e1;
    #pragma unroll
    for (int off=1; off<64; off<<=1){
        int u = __shfl_up(v, off, 64);
        if (lane>=off) v += u;
    }
    if (lane==63) wsum[wid] = v;
    __syncthreads();
    if (tid < 16){
        int w = wsum[tid];
        #pragma unroll
        for (int off=1; off<16; off<<=1){
            int u = __shfl_up(w, off, 16);
            if (tid>=off) w += u;
        }
        wsum[tid] = w;
    }
    __syncthreads();
    int base = (wid>0 ? wsum[wid-1] : 0) + (v - e1);
    segid[t0] = base + e0;
    segid[t1] = base + e1;
    __syncthreads();
    const int ns = segid[2047] + 1;
    for (int t=tid; t<2048; t+=1024){
        if (t==0 || segid[t]!=segid[t-1]) sstart[segid[t]] = t;
    }
    if (tid==0) sstart[ns] = 2048;
    __syncthreads();
    for (int t=tid; t<2048; t+=1024) out_segid[t] = (float)segid[t];
    for (int s=tid; s<2048; s+=1024)
        out_segtype[s] = (s<ns) ? (float)clips[sstart[s]] : -2147483648.0f;
    if (tid==0){ out_numseg[0] = (float)ns; wsi[0] = ns; }
    for (int s=tid; s<=2048; s+=1024) wsi[2+s] = (s<=ns) ? sstart[s] : 0;
}

__global__ __launch_bounds__(256) void segpool(
    const float* __restrict__ V, const float* __restrict__ A,
    const int* __restrict__ wsi, float* __restrict__ out_vid,
    float* __restrict__ out_aud)
{
    const int s = blockIdx.x;
    const int c = threadIdx.x*4;
    const int ns = wsi[0];
    f4 vv; vv.x=0.f; vv.y=0.f; vv.z=0.f; vv.w=0.f;
    f4 av = vv;
    if (s < ns){
        const int st = wsi[2+s], en = wsi[2+s+1];
        for (int r=st; r<en; ++r){
            f4 x = *(const f4*)(V + (size_t)r*D_MOD + c);
            vv.x+=x.x; vv.y+=x.y; vv.z+=x.z; vv.w+=x.w;
            f4 y = *(const f4*)(A + (size_t)r*D_MOD + c);
            av.x+=y.x; av.y+=y.y; av.z+=y.z; av.w+=y.w;
        }
        const float inv = 1.0f/(float)(en-st);
        vv.x*=inv; vv.y*=inv; vv.z*=inv; vv.w*=inv;
        av.x*=inv; av.y*=inv; av.z*=inv; av.w*=inv;
    }
    *(f4*)(out_vid + (size_t)s*D_MOD + c) = vv;
    *(f4*)(out_aud + (size_t)s*D_MOD + c) = av;
}

extern "C" void kernel_launch(void* const* d_in, const int* in_sizes, int n_in,
                              void* d_out, int out_size, void* d_ws, size_t ws_size,
                              hipStream_t stream) {
    (void)in_sizes; (void)n_in; (void)out_size; (void)ws_size;
    const float* video = (const float*)d_in[0];
    const float* audio = (const float*)d_in[1];
    const float* apW1  = (const float*)d_in[2];
    const float* apb1  = (const float*)d_in[3];
    const float* apW2  = (const float*)d_in[4];
    const float* apb2  = (const float*)d_in[5];
    const float* vpW1  = (const float*)d_in[6];
    const float* vpb1  = (const float*)d_in[7];
    const float* vpW2  = (const float*)d_in[8];
    const float* vpb2  = (const float*)d_in[9];
    const float* preg  = (const float*)d_in[10];
    const float* preb  = (const float*)d_in[11];
    const float* bWq   = (const float*)d_in[12];
    const float* bbq   = (const float*)d_in[13];
    const float* bWk   = (const float*)d_in[14];
    const float* bbk   = (const float*)d_in[15];
    const float* bWv   = (const float*)d_in[16];
    const float* bbv   = (const float*)d_in[17];
    const float* bWo   = (const float*)d_in[18];
    const float* bbo   = (const float*)d_in[19];
    const float* bbiask= (const float*)d_in[20];
    const float* bbiasv= (const float*)d_in[21];
    const float* bg1   = (const float*)d_in[22];
    const float* bb1   = (const float*)d_in[23];
    const float* bg2   = (const float*)d_in[24];
    const float* bb2   = (const float*)d_in[25];
    const float* bmW1  = (const float*)d_in[26];
    const float* bmb1  = (const float*)d_in[27];
    const float* bmW2  = (const float*)d_in[28];
    const float* bmb2  = (const float*)d_in[29];
    const float* lhW1  = (const float*)d_in[30];
    const float* lhb1  = (const float*)d_in[31];
    const float* lhW2  = (const float*)d_in[32];
    const float* lhb2  = (const float*)d_in[33];
    const float* thrp  = (const float*)d_in[34];

    float* ws = (float*)d_ws;
    float* V   = ws + 0;
    float* Abuf= ws + 2097152;
    float* X   = ws + 4194304;
    float* H   = ws + 6291456;
    float* Q    = ws + 8388608;
    float* Kb   = ws + 10485760;            // 2048*1024 used
    float* Vb   = ws + 12583936;            // 2048*1024 used
    float* Obuf = ws + 14682112;            // 2048*1024
    float* M4   = ws + 8388608;             // 2048*4096, aliases Q..O
    float* M512 = ws + 16779264;            // 2048*512
    float* LOC  = ws + 17827840;            // 2048
    int*   WSI  = (int*)(ws + 17829888);    // [0]=ns, [2..2050]=sstart

    float* out = (float*)d_out;
    float* out_vid     = out + 0;
    float* out_aud     = out + 2097152;
    float* out_loc     = out + 4194304;
    float* out_segid   = out + 4196352;
    float* out_segtype = out + 4198400;
    float* out_numseg  = out + 4200448;

    const dim3 B256(256);
    #define GRID128(M,N) dim3((N)/128,(M)/64)

    // projectors
    gemm128<<<GRID128(2048,512), B256, 0, stream>>>(audio, apW1, apb1, nullptr, M512, 2048,512,128, 1,0);
    gemm128<<<GRID128(2048,1024),B256, 0, stream>>>(M512, apW2, apb2, nullptr, Abuf, 2048,1024,512, 0,0);
    gemm128<<<GRID128(2048,512), B256, 0, stream>>>(video, vpW1, vpb1, nullptr, M512, 2048,512,1024, 1,0);
    gemm128<<<GRID128(2048,1024),B256, 0, stream>>>(M512, vpW2, vpb2, nullptr, V,    2048,1024,512, 0,0);
    lnrow<<<2048, B256, 0, stream>>>(Abuf, preg, preb, X, 1e-6f);

    for (int l=0; l<8; ++l){
        const size_t wo = (size_t)l*1024*1024;
        const size_t bo = (size_t)l*1024;
        const size_t mo1 = (size_t)l*1024*4096;
        lnrow<<<2048, B256, 0, stream>>>(X, bg1+bo, bb1+bo, H, 1e-5f);
        gemm128<<<GRID128(2048,1024),B256,0,stream>>>(H, bWq+wo, bbq+bo, nullptr, Q,  2048,1024,1024, 0,0);
        gemm128<<<GRID128(2048,1024),B256,0,stream>>>(V, bWk+wo, bbk+bo, nullptr, Kb, 2048,1024,1024, 0,0);
        gemm128<<<GRID128(2048,1024),B256,0,stream>>>(V, bWv+wo, bbv+bo, nullptr, Vb, 2048,1024,1024, 0,0);
        attn64<<<256, dim3(512), 0, stream>>>(Q, Kb, Vb, bbiask+bo, bbiasv+bo, Obuf);
        gemm128<<<GRID128(2048,1024),B256,0,stream>>>(Obuf, bWo+wo, bbo+bo, X, X, 2048,1024,1024, 0,1);
        lnrow<<<2048, B256, 0, stream>>>(X, bg2+bo, bb2+bo, H, 1e-5f);
        gemm128<<<GRID128(2048,4096),B256,0,stream>>>(H, bmW1+mo1, bmb1+(size_t)l*4096, nullptr, M4, 2048,4096,1024, 2,0);
        gemm128<<<GRID128(2048,1024),B256,0,stream>>>(M4, bmW2+mo1, bmb2+bo, X, X, 2048,1024,4096, 0,1);
    }

    gemm128<<<GRID128(2048,512), B256, 0, stream>>>(X, lhW1, lhb1, nullptr, M512, 2048,512,1024, 1,0);
    locate_head<<<2048, dim3(64), 0, stream>>>(M512, lhW2, lhb2, LOC, out_loc);
    segscan<<<1, dim3(1024), 0, stream>>>(LOC, thrp, out_segid, out_segtype, out_numseg, WSI);
    segpool<<<2048, B256, 0, stream>>>(V, Abuf, WSI, out_vid, out_aud);
}